// Round 1
// baseline (47652.936 us; speedup 1.0000x reference)
//
#include <hip/hip_runtime.h>
#include <math.h>

// ESN recurrence: x_t = tanh(w_in*u_t + W x_{t-1}); out[t-washout] = c . x_t
// R15: split DETECTION from DATA in the cross-block exchange.
// Theory: the 4.1us/step plateau (invariant to sync mechanism/fences/RMWs/
// participants in R10-R14) is LLC poll-storm congestion: data-embedded epoch
// tags force every sweep to re-read the whole 16KB payload (256 lines/block-
// sweep, 65K line-txns per device sweep, several sweeps/step). New scheme:
//  - values: packed (x[2j]|x[2j+1]) ull, 4 agent exchanges per block
//  - readiness: ONE uint epoch flag per producer block (256 flags = 16 lines;
//    device sweep cost drops 16x). tid0 publishes it after the post-dot
//    __syncthreads + explicit s_waitcnt vmcnt(0), so all waves' value
//    exchanges are ACKed at the LLC before the flag issues (release order
//    without buffer_wbl2).
//  - consumer thread t polls flag[t] only, then bulk-fetches producer t's
//    4 ulls once and stages to LDS; per-thread progress overlaps straggler
//    wait with value fetches of already-finished producers.
// Overwrite safety: block at step k sees all flags_k => every block's every
// thread passed step k-1's post-stage barrier => x_{k-1} fully consumed into
// LDS => overwriting buffer (k+1)&1 is safe (same induction as R9).
// Prediction: congestion-dominated -> ~2.8-3.3us/step (dur ~23-27ms),
// FETCH_SIZE down; latency-dominated -> neutral-to-+8% (one extra LLC hop),
// which would falsify H1 and establish the sync-latency floor.

#define H_   2048
#define RPB  8          // rows per block
#define NBLK 256
typedef unsigned long long ull;
// ws layout (float idx):
//   [0,4096)       ull xval[2][1024]: value pairs (x[2j] | x[2j+1]<<32)
//   [4096,4608)    uint flag[2][256]: per-producer-block epoch
//   [8192,10240)   float c (scatter of w_out by mask)
//   [10240, 10240+T*256)  part (per-step per-block partials, plain store)

__global__ void esn_zero(float* __restrict__ p, int n)
{
    int i = blockIdx.x * blockDim.x + threadIdx.x;
    int stride = gridDim.x * blockDim.x;
    for (; i < n; i += stride) p[i] = 0.0f;
}

__global__ __launch_bounds__(1024) void esn_scatter_c(const int* __restrict__ mask,
                                                      const float* __restrict__ w_out,
                                                      float* __restrict__ ws_f, int H)
{
    float* c = ws_f + 8192;
    for (int i = threadIdx.x; i < H; i += blockDim.x)
        atomicAdd(&c[mask[i]], w_out[i]);
}

__global__ __launch_bounds__(256) void esn_run(const float* __restrict__ u,
                                               const float* __restrict__ w_res,
                                               const float* __restrict__ w_in,
                                               float* __restrict__ out,
                                               float* __restrict__ ws_f,
                                               int T, int washout, int use_part)
{
    __shared__ float Wlds[RPB * H_];   // 64 KB
    __shared__ float xs[H_];
    __shared__ float psum[4];

    const int tid  = threadIdx.x;
    const int wave = tid >> 6;
    const int lane = tid & 63;
    const int bid  = blockIdx.x;
    const int r0 = 2 * wave;
    const int grow0 = bid * RPB + r0, grow1 = grow0 + 1;

    {
        const float4* src = (const float4*)(w_res + (size_t)bid * RPB * H_);
        float4* dst = (float4*)Wlds;
        for (int i = tid; i < RPB * H_ / 4; i += 256) dst[i] = src[i];
    }
    float win0 = 0.f, win1 = 0.f, c0 = 0.f, c1 = 0.f;
    if (lane == 0) {
        win0 = w_in[grow0]; win1 = w_in[grow1];
        c0 = ws_f[8192 + grow0]; c1 = ws_f[8192 + grow1];
    }

    ull*          xv = (ull*)ws_f;                   // [2][1024]
    unsigned int* fl = (unsigned int*)(ws_f + 4096); // [2][256]
    float* part = ws_f + 10240;

    const float4* w0p = (const float4*)(Wlds + r0 * H_);
    const float4* w1p = (const float4*)(Wlds + (r0 + 1) * H_);
    const float4* xs4 = (const float4*)xs;
    float4* xs4w = (float4*)xs;

    float u_next = u[0];
    __syncthreads();   // Wlds ready

    for (int k = 0; k < T; ++k) {
        const ull*    sp = xv + (k & 1) * 1024 + 4 * tid;
        ull*          dp = xv + ((k + 1) & 1) * 1024;
        unsigned int* sf = fl + (k & 1) * 256;
        unsigned int* df = fl + ((k + 1) & 1) * 256;
        float uk = u_next;
        if (k + 1 < T) u_next = u[k + 1];

        // ---- wait for producer block 'tid' to publish x_k (1 line / 16 threads) ----
        {
            int spins = 0;
            for (;;) {
                unsigned int f = __hip_atomic_load(sf + tid, __ATOMIC_RELAXED,
                                                   __HIP_MEMORY_SCOPE_AGENT);
                if (f == (unsigned int)k) break;
                if (++spins > 500000) break; // failsafe
            }
        }
        __builtin_amdgcn_sched_barrier(0);   // no speculative hoist of value loads

        // ---- bulk-fetch producer tid's 8 values (once), stage to LDS ----
        {
            ull v0 = __hip_atomic_load(sp + 0, __ATOMIC_RELAXED, __HIP_MEMORY_SCOPE_AGENT);
            ull v1 = __hip_atomic_load(sp + 1, __ATOMIC_RELAXED, __HIP_MEMORY_SCOPE_AGENT);
            ull v2 = __hip_atomic_load(sp + 2, __ATOMIC_RELAXED, __HIP_MEMORY_SCOPE_AGENT);
            ull v3 = __hip_atomic_load(sp + 3, __ATOMIC_RELAXED, __HIP_MEMORY_SCOPE_AGENT);
            float4 a, b;
            a.x = __uint_as_float((unsigned int)v0);
            a.y = __uint_as_float((unsigned int)(v0 >> 32));
            a.z = __uint_as_float((unsigned int)v1);
            a.w = __uint_as_float((unsigned int)(v1 >> 32));
            b.x = __uint_as_float((unsigned int)v2);
            b.y = __uint_as_float((unsigned int)(v2 >> 32));
            b.z = __uint_as_float((unsigned int)v3);
            b.w = __uint_as_float((unsigned int)(v3 >> 32));
            xs4w[2 * tid]     = a;
            xs4w[2 * tid + 1] = b;
        }
        __syncthreads();   // xs ready (also: every thread has consumed x_k)

        // ---- dot: wave owns rows r0, r0+1 ----
        float4 a0 = {0.f,0.f,0.f,0.f}, a1 = {0.f,0.f,0.f,0.f};
#pragma unroll
        for (int c = 0; c < 8; ++c) {
            float4 xvv = xs4[c * 64 + lane];
            float4 wv0 = w0p[c * 64 + lane];
            float4 wv1 = w1p[c * 64 + lane];
            a0.x = fmaf(wv0.x, xvv.x, a0.x); a0.y = fmaf(wv0.y, xvv.y, a0.y);
            a0.z = fmaf(wv0.z, xvv.z, a0.z); a0.w = fmaf(wv0.w, xvv.w, a0.w);
            a1.x = fmaf(wv1.x, xvv.x, a1.x); a1.y = fmaf(wv1.y, xvv.y, a1.y);
            a1.z = fmaf(wv1.z, xvv.z, a1.z); a1.w = fmaf(wv1.w, xvv.w, a1.w);
        }
        float s0 = (a0.x + a0.y) + (a0.z + a0.w);
        float s1 = (a1.x + a1.y) + (a1.z + a1.w);
#pragma unroll
        for (int d = 1; d < 64; d <<= 1) {
            s0 += __shfl_xor(s0, d);
            s1 += __shfl_xor(s1, d);
        }

        if (lane == 0) {
            float z0 = fmaf(win0, uk, s0);
            float z1 = fmaf(win1, uk, s1);
            z0 = fminf(fmaxf(z0, -15.f), 15.f);
            z1 = fminf(fmaxf(z1, -15.f), 15.f);
            float e0 = __expf(2.f * z0), e1 = __expf(2.f * z1);
            float t0 = (e0 - 1.f) / (e0 + 1.f), t1 = (e1 - 1.f) / (e1 + 1.f);
            ull p01 = (ull)__float_as_uint(t0) | ((ull)__float_as_uint(t1) << 32);
            // exchange: commits at the far unit (no writeback lag)
            (void)__hip_atomic_exchange(dp + (bid * 4 + wave), p01,
                                        __ATOMIC_RELAXED, __HIP_MEMORY_SCOPE_AGENT);
            psum[wave] = c0 * t0 + c1 * t1;
        }
        // explicit drain: every wave's value exchange ACKed at the LLC before
        // the barrier releases tid0's flag store (belt for the implicit
        // vmcnt(0)-before-s_barrier the compiler emits anyway)
        asm volatile("s_waitcnt vmcnt(0)" ::: "memory");
        __syncthreads();   // psum ready; all value exchanges globally visible

        if (tid == 0) {
            (void)__hip_atomic_exchange(df + bid, (unsigned int)(k + 1),
                                        __ATOMIC_RELAXED, __HIP_MEMORY_SCOPE_AGENT);
            float pw = (psum[0] + psum[1]) + (psum[2] + psum[3]);
            if (use_part) part[(size_t)k * NBLK + bid] = pw;
            else if (k >= washout) atomicAdd(&out[k - washout], pw);
        }
    }
}

__global__ __launch_bounds__(256) void esn_reduce(const float* __restrict__ part,
                                                  float* __restrict__ out,
                                                  int out_size, int washout)
{
    int wv = threadIdx.x >> 6, lane = threadIdx.x & 63;
    int t = blockIdx.x * 4 + wv;
    if (t >= out_size) return;
    const float4* p = (const float4*)(part + (size_t)(t + washout) * NBLK);
    float4 v = p[lane];
    float s = (v.x + v.y) + (v.z + v.w);
#pragma unroll
    for (int d = 1; d < 64; d <<= 1) s += __shfl_xor(s, d);
    if (lane == 0) out[t] = s;
}

extern "C" void kernel_launch(void* const* d_in, const int* in_sizes, int n_in,
                              void* d_out, int out_size, void* d_ws, size_t ws_size,
                              hipStream_t stream)
{
    const float* u     = (const float*)d_in[0];
    const float* w_res = (const float*)d_in[1];
    const float* w_in  = (const float*)d_in[2];
    const float* w_out = (const float*)d_in[3];
    const int*   mask  = (const int*)d_in[4];
    int T = in_sizes[0];
    int H = in_sizes[2];
    int washout = T - out_size;
    float* out  = (float*)d_out;
    float* ws_f = (float*)d_ws;

    size_t need = (size_t)(10240 + (size_t)T * NBLK) * 4;
    int use_part = (ws_size >= need) ? 1 : 0;

    hipLaunchKernelGGL(esn_zero, dim3(64), dim3(256), 0, stream, ws_f, 10240);
    if (!use_part)   // direct-atomic fallback needs out pre-zeroed
        hipLaunchKernelGGL(esn_zero, dim3(32), dim3(256), 0, stream, out, out_size);
    hipLaunchKernelGGL(esn_scatter_c, dim3(1), dim3(1024), 0, stream, mask, w_out, ws_f, H);

    void* args[] = { (void*)&u, (void*)&w_res, (void*)&w_in, (void*)&out,
                     (void*)&ws_f, (void*)&T, (void*)&washout, (void*)&use_part };
    hipError_t e = hipLaunchCooperativeKernel((const void*)esn_run,
                                              dim3(NBLK), dim3(256),
                                              args, 0, stream);
    if (e != hipSuccess) {
        hipLaunchKernelGGL(esn_run, dim3(NBLK), dim3(256), 0, stream,
                           u, w_res, w_in, out, ws_f, T, washout, use_part);
    }
    if (use_part)
        hipLaunchKernelGGL(esn_reduce, dim3((out_size + 3) / 4), dim3(256), 0, stream,
                           ws_f + 10240, out, out_size, washout);
}

// Round 2
// 32943.109 us; speedup vs baseline: 1.4465x; 1.4465x over previous
//
#include <hip/hip_runtime.h>
#include <math.h>

// ESN recurrence: x_t = tanh(w_in*u_t + W x_{t-1}); out[t-washout] = c . x_t
// R16 = R14's proven single-hop protocol (data-embedded epoch tags, the
// measured 33.3ms optimum) + 8x REPLICATED value buffers to de-contend the
// LLC poll lines.
// Post-mortem R15: splitting detection (flags) from data added ~2 serial LLC
// hops (+1.75us/step) AND concentrated pollers 16x -> 47.7ms, high variance.
// Falsified nothing; reverted entirely.
// R16 theory: R14's 4.07us/step >> chain latency (~1.2us). Excess attributed
// to LLC bank queueing: each pair-line is spin-loaded by ~256 blocks, and the
// producer's exchange queues BEHIND that storm at the same bank. Fix keeps
// hop count identical but cuts pollers/line 8x:
//  - producers write each (epoch|value) ull to 8 replica buffers
//    (lanes 0..7 of each wave: 2 exchanges each, fire-and-forget)
//  - consumer block b polls ONLY replica (b&7); replicas are line-disjoint
// Overwrite safety: same induction as R9/R14 -- block publishing epoch k+1
// has consumed all of x_k, hence every block published x_k, hence every
// block finished staging x_{k-1}; max phase skew < 2 steps.
// Prediction: contention-dominated -> 2.7-3.3us/step (22-27ms), WRITE_SIZE
// ~2x, LDS conflicts ~0; latency-dominated -> neutral (33-34ms), which would
// establish the single-hop sync floor.

#define H_   2048
#define RPB  8          // rows per block
#define NBLK 256
#define NREP 8          // value-buffer replicas
typedef unsigned long long ull;
// ws layout (float idx):
//   [0, 65536)      ull xval[NREP][2][2048]: per-replica, per-parity
//                   (epoch<<32 | value) for each x element. 256 KB.
//   [65536, 67584)  float c (scatter of w_out by mask)
//   [67584, 67584+T*256)  part (per-step per-block partials, plain store)

__global__ void esn_zero(float* __restrict__ p, int n)
{
    int i = blockIdx.x * blockDim.x + threadIdx.x;
    int stride = gridDim.x * blockDim.x;
    for (; i < n; i += stride) p[i] = 0.0f;
}

__global__ __launch_bounds__(1024) void esn_scatter_c(const int* __restrict__ mask,
                                                      const float* __restrict__ w_out,
                                                      float* __restrict__ ws_f, int H)
{
    float* c = ws_f + 65536;
    for (int i = threadIdx.x; i < H; i += blockDim.x)
        atomicAdd(&c[mask[i]], w_out[i]);
}

__global__ __launch_bounds__(256) void esn_run(const float* __restrict__ u,
                                               const float* __restrict__ w_res,
                                               const float* __restrict__ w_in,
                                               float* __restrict__ out,
                                               float* __restrict__ ws_f,
                                               int T, int washout, int use_part)
{
    __shared__ float Wlds[RPB * H_];   // 64 KB
    __shared__ float xs[H_];
    __shared__ float psum[4];

    const int tid  = threadIdx.x;
    const int wave = tid >> 6;
    const int lane = tid & 63;
    const int bid  = blockIdx.x;
    const int r0 = 2 * wave;
    const int grow0 = bid * RPB + r0, grow1 = grow0 + 1;

    {
        const float4* src = (const float4*)(w_res + (size_t)bid * RPB * H_);
        float4* dst = (float4*)Wlds;
        for (int i = tid; i < RPB * H_ / 4; i += 256) dst[i] = src[i];
    }
    float win0 = 0.f, win1 = 0.f, c0 = 0.f, c1 = 0.f;
    if (lane == 0) {
        win0 = w_in[grow0]; win1 = w_in[grow1];
        c0 = ws_f[65536 + grow0]; c1 = ws_f[65536 + grow1];
    }

    ull* xv = (ull*)ws_f;              // [NREP][2][2048]
    float* part = ws_f + 67584;

    const float4* w0p = (const float4*)(Wlds + r0 * H_);
    const float4* w1p = (const float4*)(Wlds + (r0 + 1) * H_);
    const float4* xs4 = (const float4*)xs;

    // this block reads replica (bid & 7) only
    const ull* rbase = xv + (size_t)(bid & (NREP - 1)) * 4096;

    float u_next = u[0];
    __syncthreads();   // Wlds ready

    for (int k = 0; k < T; ++k) {
        const ull* sp = rbase + (k & 1) * 2048;
        float uk = u_next;
        if (k + 1 < T) u_next = u[k + 1];

        // ---- stage x_k: batch load, then PARALLEL-retry sweeps (R14 form) ----
        ull pv[8];
#pragma unroll
        for (int i = 0; i < 8; ++i)
            pv[i] = __hip_atomic_load(sp + (i << 8) + tid, __ATOMIC_RELAXED,
                                      __HIP_MEMORY_SCOPE_AGENT);
        {
            int spins = 0;
            for (;;) {
                unsigned pend = 0;
#pragma unroll
                for (int i = 0; i < 8; ++i)
                    if ((unsigned)(pv[i] >> 32) != (unsigned)k) {
                        pv[i] = __hip_atomic_load(sp + (i << 8) + tid,
                                                  __ATOMIC_RELAXED,
                                                  __HIP_MEMORY_SCOPE_AGENT);
                        pend = 1;
                    }
                if (!pend) break;
                if (++spins > 500000) break; // failsafe
            }
        }
#pragma unroll
        for (int i = 0; i < 8; ++i)
            xs[(i << 8) + tid] = __uint_as_float((unsigned)pv[i]);
        __syncthreads();

        // ---- dot: wave owns rows r0, r0+1 ----
        float4 a0 = {0.f,0.f,0.f,0.f}, a1 = {0.f,0.f,0.f,0.f};
#pragma unroll
        for (int c = 0; c < 8; ++c) {
            float4 xvv = xs4[c * 64 + lane];
            float4 wv0 = w0p[c * 64 + lane];
            float4 wv1 = w1p[c * 64 + lane];
            a0.x = fmaf(wv0.x, xvv.x, a0.x); a0.y = fmaf(wv0.y, xvv.y, a0.y);
            a0.z = fmaf(wv0.z, xvv.z, a0.z); a0.w = fmaf(wv0.w, xvv.w, a0.w);
            a1.x = fmaf(wv1.x, xvv.x, a1.x); a1.y = fmaf(wv1.y, xvv.y, a1.y);
            a1.z = fmaf(wv1.z, xvv.z, a1.z); a1.w = fmaf(wv1.w, xvv.w, a1.w);
        }
        float s0 = (a0.x + a0.y) + (a0.z + a0.w);
        float s1 = (a1.x + a1.y) + (a1.z + a1.w);
#pragma unroll
        for (int d = 1; d < 64; d <<= 1) {
            s0 += __shfl_xor(s0, d);
            s1 += __shfl_xor(s1, d);
        }

        ull p0 = 0, p1 = 0;
        if (lane == 0) {
            float z0 = fmaf(win0, uk, s0);
            float z1 = fmaf(win1, uk, s1);
            z0 = fminf(fmaxf(z0, -15.f), 15.f);
            z1 = fminf(fmaxf(z1, -15.f), 15.f);
            float e0 = __expf(2.f * z0), e1 = __expf(2.f * z1);
            float t0 = (e0 - 1.f) / (e0 + 1.f), t1 = (e1 - 1.f) / (e1 + 1.f);
            p0 = ((ull)(unsigned)(k + 1) << 32) | (ull)__float_as_uint(t0);
            p1 = ((ull)(unsigned)(k + 1) << 32) | (ull)__float_as_uint(t1);
            psum[wave] = c0 * t0 + c1 * t1;
        }
        // broadcast the tagged pairs; lanes 0..7 publish replica 'lane'
        p0 = __shfl(p0, 0, 64);
        p1 = __shfl(p1, 0, 64);
        if (lane < NREP) {
            ull* dpr = xv + (size_t)lane * 4096 + ((k + 1) & 1) * 2048;
            // exchange: commits at the far unit (no writeback lag)
            (void)__hip_atomic_exchange(dpr + grow0, p0, __ATOMIC_RELAXED,
                                        __HIP_MEMORY_SCOPE_AGENT);
            (void)__hip_atomic_exchange(dpr + grow1, p1, __ATOMIC_RELAXED,
                                        __HIP_MEMORY_SCOPE_AGENT);
        }
        __syncthreads();   // psum ready; xs reads done (safe to restage)

        if (tid == 0) {
            float pw = (psum[0] + psum[1]) + (psum[2] + psum[3]);
            if (use_part) part[(size_t)k * NBLK + bid] = pw;
            else if (k >= washout) atomicAdd(&out[k - washout], pw);
        }
    }
}

__global__ __launch_bounds__(256) void esn_reduce(const float* __restrict__ part,
                                                  float* __restrict__ out,
                                                  int out_size, int washout)
{
    int wv = threadIdx.x >> 6, lane = threadIdx.x & 63;
    int t = blockIdx.x * 4 + wv;
    if (t >= out_size) return;
    const float4* p = (const float4*)(part + (size_t)(t + washout) * NBLK);
    float4 v = p[lane];
    float s = (v.x + v.y) + (v.z + v.w);
#pragma unroll
    for (int d = 1; d < 64; d <<= 1) s += __shfl_xor(s, d);
    if (lane == 0) out[t] = s;
}

extern "C" void kernel_launch(void* const* d_in, const int* in_sizes, int n_in,
                              void* d_out, int out_size, void* d_ws, size_t ws_size,
                              hipStream_t stream)
{
    const float* u     = (const float*)d_in[0];
    const float* w_res = (const float*)d_in[1];
    const float* w_in  = (const float*)d_in[2];
    const float* w_out = (const float*)d_in[3];
    const int*   mask  = (const int*)d_in[4];
    int T = in_sizes[0];
    int H = in_sizes[2];
    int washout = T - out_size;
    float* out  = (float*)d_out;
    float* ws_f = (float*)d_ws;

    size_t need = (size_t)(67584 + (size_t)T * NBLK) * 4;
    int use_part = (ws_size >= need) ? 1 : 0;

    hipLaunchKernelGGL(esn_zero, dim3(128), dim3(256), 0, stream, ws_f, 67584);
    if (!use_part)   // direct-atomic fallback needs out pre-zeroed
        hipLaunchKernelGGL(esn_zero, dim3(32), dim3(256), 0, stream, out, out_size);
    hipLaunchKernelGGL(esn_scatter_c, dim3(1), dim3(1024), 0, stream, mask, w_out, ws_f, H);

    void* args[] = { (void*)&u, (void*)&w_res, (void*)&w_in, (void*)&out,
                     (void*)&ws_f, (void*)&T, (void*)&washout, (void*)&use_part };
    hipError_t e = hipLaunchCooperativeKernel((const void*)esn_run,
                                              dim3(NBLK), dim3(256),
                                              args, 0, stream);
    if (e != hipSuccess) {
        hipLaunchKernelGGL(esn_run, dim3(NBLK), dim3(256), 0, stream,
                           u, w_res, w_in, out, ws_f, T, washout, use_part);
    }
    if (use_part)
        hipLaunchKernelGGL(esn_reduce, dim3((out_size + 3) / 4), dim3(256), 0, stream,
                           ws_f + 67584, out, out_size, washout);
}